// Round 4
// baseline (201.358 us; speedup 1.0000x reference)
//
#include <hip/hip_runtime.h>
#include <math.h>

#define F 256
#define TBL 4096
#define TBLK (TBL / 16)      // 256 table-builder blocks; block TBLK does u/c0 prep
#define SMAX 8.0f
#define EPS 1e-8f
#define MAXROWS 512          // LDS a-buffer capacity per batch (avg batch = 73 rows)

typedef float f4 __attribute__((ext_vector_type(4)));

__device__ __forceinline__ float softplus_f(float t) {
    return fmaxf(t, 0.f) + log1pf(expf(-fabsf(t)));
}

__device__ __forceinline__ int lower_bound_i(const int* __restrict__ seg, int n, int v) {
    int lo = 0, hi = n;
    while (lo < hi) {
        int mid = (lo + hi) >> 1;
        if (seg[mid] < v) lo = mid + 1; else hi = mid;
    }
    return lo;
}

// ---------------------------------------------------------------------------
// k_table: blocks [0,TBLK): lookup table g(s) = s*Wv + h2(s), 16 rows/block
//          block TBLK:       u = Wq @ Wk, c0 = Wk . bq
// ---------------------------------------------------------------------------
__global__ __launch_bounds__(256)
void k_table(const float* __restrict__ Wq, const float* __restrict__ bq,
             const float* __restrict__ Wk, const float* __restrict__ Wv,
             const float* __restrict__ W1, const float* __restrict__ b1,
             const float* __restrict__ W2, const float* __restrict__ b2,
             float* __restrict__ u, float* __restrict__ c0,
             float* __restrict__ table)
{
    __shared__ float zbuf[16][F];   // 16 KB
    const int i = threadIdx.x;

    if ((int)blockIdx.x == TBLK) {
        // ----- prep: u[g] = sum_f Wk[f]*Wq[f,g]; c0 = Wk.bq -----
        __shared__ float wk_s[F];
        __shared__ float red[F];
        wk_s[i] = Wk[i];
        __syncthreads();
        float acc = 0.f;
        #pragma unroll 4
        for (int f = 0; f < F; ++f)
            acc += wk_s[f] * Wq[f * F + i];
        u[i] = acc;
        red[i] = wk_s[i] * bq[i];
        __syncthreads();
        for (int s = 128; s > 0; s >>= 1) {
            if (i < s) red[i] += red[i + s];
            __syncthreads();
        }
        if (i == 0) *c0 = red[0];
        return;
    }

    // ----- table build -----
    const int tb = blockIdx.x;
    const float delta = SMAX / (float)(TBL - 1);
    const float wv = Wv[i];

    #pragma unroll
    for (int r = 0; r < 16; ++r) {
        float s  = (float)(tb * 16 + r) * delta;
        float zv = s * wv;
        zbuf[r][i] = zv / (1.f + __expf(-zv));               // silu(y)
    }
    __syncthreads();

    float acc[16];
    float bb = b1[i];
    #pragma unroll
    for (int r = 0; r < 16; ++r) acc[r] = bb;
    const f4* w1row = (const f4*)(W1 + (size_t)i * F);
    for (int fc = 0; fc < F / 4; ++fc) {
        f4 w4 = w1row[fc];
        #pragma unroll
        for (int r = 0; r < 16; ++r) {
            f4 z4 = *(const f4*)&zbuf[r][fc * 4];            // uniform broadcast
            acc[r] += w4.x * z4.x + w4.y * z4.y + w4.z * z4.z + w4.w * z4.w;
        }
    }
    __syncthreads();
    #pragma unroll
    for (int r = 0; r < 16; ++r)
        zbuf[r][i] = acc[r] / (1.f + __expf(-acc[r]));       // silu(h1)
    __syncthreads();

    bb = b2[i];
    #pragma unroll
    for (int r = 0; r < 16; ++r) acc[r] = bb;
    const f4* w2row = (const f4*)(W2 + (size_t)i * F);
    for (int fc = 0; fc < F / 4; ++fc) {
        f4 w4 = w2row[fc];
        #pragma unroll
        for (int r = 0; r < 16; ++r) {
            f4 z4 = *(const f4*)&zbuf[r][fc * 4];
            acc[r] += w4.x * z4.x + w4.y * z4.y + w4.z * z4.z + w4.w * z4.w;
        }
    }
    #pragma unroll
    for (int r = 0; r < 16; ++r) {
        float s = (float)(tb * 16 + r) * delta;
        table[(size_t)(tb * 16 + r) * F + i] = s * wv + acc[r];
    }
}

// ---------------------------------------------------------------------------
// k_fused: one block per batch b. Rows [lo,hi) found by binary search (seg
// sorted). Pass 1: a[r] = softplus(|E|*(u.x_r + c0)/16) -> LDS, block-sum
// anorm (exact, no atomics). Pass 2: s = a*|E|/(anorm+eps), lerp table, write.
// ---------------------------------------------------------------------------
__global__ __launch_bounds__(256)
void k_fused(const float* __restrict__ x, const float* __restrict__ E,
             const int* __restrict__ seg, const float* __restrict__ u,
             const float* __restrict__ c0p, const float* __restrict__ table,
             float* __restrict__ out, int N)
{
    __shared__ float abuf[MAXROWS];
    __shared__ float wsum[4];

    const int b    = blockIdx.x;
    const int lane = threadIdx.x & 63;
    const int wid  = threadIdx.x >> 6;

    // uniform binary searches (all lanes same address -> broadcast loads)
    const int lo = lower_bound_i(seg, N, b);
    const int hi = lower_bound_i(seg, N, b + 1);
    if (lo >= hi) return;

    const f4 u4    = ((const f4*)u)[lane];
    const float c0 = *c0p;
    const float e  = fabsf(E[b]);

    // ----- pass 1: dots + softplus, a -> LDS, partial sums -----
    float partial = 0.f;
    for (int rr = lo + wid * 2; rr < hi; rr += 8) {
        const f4* xp0 = (const f4*)(x + (size_t)rr * F) + lane;
        f4 r0 = __builtin_nontemporal_load(xp0);
        float d0 = r0.x * u4.x + r0.y * u4.y + r0.z * u4.z + r0.w * u4.w;
        bool two = (rr + 1) < hi;
        f4 r1;
        if (two) r1 = __builtin_nontemporal_load(xp0 + 64);
        float d1 = two ? (r1.x * u4.x + r1.y * u4.y + r1.z * u4.z + r1.w * u4.w) : 0.f;
        #pragma unroll
        for (int off = 32; off; off >>= 1) {
            d0 += __shfl_xor(d0, off);
            d1 += __shfl_xor(d1, off);
        }
        float a0 = softplus_f(e * (d0 + c0) * 0.0625f);
        partial += a0;
        int idx = rr - lo;
        if (lane == 0 && idx < MAXROWS) abuf[idx] = a0;
        if (two) {
            float a1 = softplus_f(e * (d1 + c0) * 0.0625f);
            partial += a1;
            if (lane == 0 && idx + 1 < MAXROWS) abuf[idx + 1] = a1;
        }
    }
    if (lane == 0) wsum[wid] = partial;
    __syncthreads();
    const float anorm = wsum[0] + wsum[1] + wsum[2] + wsum[3];
    const float sscale = e / (anorm + EPS);          // s = a * sscale
    const float inv_delta = (float)(TBL - 1) / SMAX;

    // ----- pass 2: lerp table, write out -----
    for (int rr = lo + wid * 2; rr < hi; rr += 8) {
        #pragma unroll
        for (int k = 0; k < 2; ++k) {
            int r = rr + k;
            if (r >= hi) break;
            int idx = r - lo;
            float a;
            if (idx < MAXROWS) {
                a = abuf[idx];                       // broadcast
            } else {                                 // ultra-rare fallback
                const f4* xp = (const f4*)(x + (size_t)r * F) + lane;
                f4 rx = *xp;
                float d = rx.x * u4.x + rx.y * u4.y + rx.z * u4.z + rx.w * u4.w;
                #pragma unroll
                for (int off = 32; off; off >>= 1) d += __shfl_xor(d, off);
                a = softplus_f(e * (d + c0) * 0.0625f);
            }
            float pos = a * sscale * inv_delta;
            int i0 = (int)pos;
            i0 = min(max(i0, 0), TBL - 2);
            float frac = pos - (float)i0;
            const f4 g0 = ((const f4*)(table + (size_t)i0 * F))[lane];
            const f4 g1 = ((const f4*)(table + (size_t)(i0 + 1) * F))[lane];
            f4 o;
            o.x = g0.x + frac * (g1.x - g0.x);
            o.y = g0.y + frac * (g1.y - g0.y);
            o.z = g0.z + frac * (g1.z - g0.z);
            o.w = g0.w + frac * (g1.w - g0.w);
            __builtin_nontemporal_store(o, (f4*)(out + (size_t)r * F) + lane);
        }
    }
}

// ---------------------------------------------------------------------------
extern "C" void kernel_launch(void* const* d_in, const int* in_sizes, int n_in,
                              void* d_out, int out_size, void* d_ws, size_t ws_size,
                              hipStream_t stream)
{
    const float* x   = (const float*)d_in[0];
    const float* E   = (const float*)d_in[1];
    const int*   seg = (const int*)  d_in[2];
    const float* Wq  = (const float*)d_in[4];
    const float* bq  = (const float*)d_in[5];
    const float* Wk  = (const float*)d_in[6];
    const float* Wv  = (const float*)d_in[7];
    const float* W1  = (const float*)d_in[8];
    const float* b1  = (const float*)d_in[9];
    const float* W2  = (const float*)d_in[10];
    const float* b2  = (const float*)d_in[11];

    const int N = in_sizes[0] / F;
    const int B = in_sizes[1];
    float* out = (float*)d_out;

    float* ws    = (float*)d_ws;
    float* table = ws;                          // TBL*F floats (4 MB)
    float* u     = table + (size_t)TBL * F;     // F
    float* c0    = u + F;                       // 1

    k_table<<<TBLK + 1, 256, 0, stream>>>(Wq, bq, Wk, Wv, W1, b1, W2, b2,
                                          u, c0, table);

    k_fused<<<B, 256, 0, stream>>>(x, E, seg, u, c0, table, out, N);
}

// Round 5
// 176.252 us; speedup vs baseline: 1.1424x; 1.1424x over previous
//
#include <hip/hip_runtime.h>
#include <math.h>

#define F 256
#define TBL 4096
#define TBLK (TBL / 16)
#define GA 1792
#define SMAX 8.0f
#define EPS 1e-8f

typedef float f4 __attribute__((ext_vector_type(4)));

__device__ __forceinline__ float softplus_f(float t) {
    return fmaxf(t, 0.f) + log1pf(expf(-fabsf(t)));
}

__global__ __launch_bounds__(256)
void k_prep(const float* __restrict__ Wq, const float* __restrict__ bq,
            const float* __restrict__ Wk, float* __restrict__ u,
            float* __restrict__ c0, float* __restrict__ anorm, int B)
{
    __shared__ float wk_s[F];
    __shared__ float red[F];
    int g = threadIdx.x;
    for (int j = g; j < B; j += 256) anorm[j] = 0.f;
    wk_s[g] = Wk[g];
    __syncthreads();
    float acc = 0.f;
    #pragma unroll 4
    for (int f = 0; f < F; ++f)
        acc += wk_s[f] * Wq[f * F + g];
    u[g] = acc;

    red[g] = wk_s[g] * bq[g];
    __syncthreads();
    for (int s = 128; s > 0; s >>= 1) {
        if (g < s) red[g] += red[g + s];
        __syncthreads();
    }
    if (g == 0) *c0 = red[0];
}

__global__ __launch_bounds__(256)
void k_main(const float* __restrict__ x, const float* __restrict__ E,
            const int* __restrict__ seg, const float* __restrict__ u,
            const float* __restrict__ c0p, const float* __restrict__ Wv,
            const float* __restrict__ W1, const float* __restrict__ b1,
            const float* __restrict__ W2, const float* __restrict__ b2,
            float* __restrict__ a_arr, float* __restrict__ anorm,
            float* __restrict__ table, int N)
{
    __shared__ float zbuf[16][F];

    if ((int)blockIdx.x >= TBLK) {
        const int lane = threadIdx.x & 63;
        const int wid  = threadIdx.x >> 6;
        const int gwave = (blockIdx.x - TBLK) * 4 + wid;
        const int total_waves = GA * 4;
        const int chunk = (N + total_waves - 1) / total_waves;
        const int n0 = gwave * chunk;
        const int n1 = min(n0 + chunk, N);
        if (n0 >= n1) return;

        const f4 u4 = ((const f4*)u)[lane];
        const float c0 = *c0p;

        int   curb = seg[n0];
        float accA = 0.f;

        int n = n0;
        for (; n + 3 < n1; n += 4) {
            const f4* xp = (const f4*)(x + (size_t)n * F) + lane;
            f4 r0 = xp[0];
            f4 r1 = xp[64];
            f4 r2 = xp[128];
            f4 r3 = xp[192];
            float d0 = r0.x * u4.x + r0.y * u4.y + r0.z * u4.z + r0.w * u4.w;
            float d1 = r1.x * u4.x + r1.y * u4.y + r1.z * u4.z + r1.w * u4.w;
            float d2 = r2.x * u4.x + r2.y * u4.y + r2.z * u4.z + r2.w * u4.w;
            float d3 = r3.x * u4.x + r3.y * u4.y + r3.z * u4.z + r3.w * u4.w;
            #pragma unroll
            for (int off = 32; off; off >>= 1) {
                d0 += __shfl_xor(d0, off);
                d1 += __shfl_xor(d1, off);
                d2 += __shfl_xor(d2, off);
                d3 += __shfl_xor(d3, off);
            }
            int b0 = seg[n], b1i = seg[n + 1], b2i = seg[n + 2], b3 = seg[n + 3];
            float a0 = softplus_f(fabsf(E[b0])  * (d0 + c0) * 0.0625f);
            float a1 = softplus_f(fabsf(E[b1i]) * (d1 + c0) * 0.0625f);
            float a2 = softplus_f(fabsf(E[b2i]) * (d2 + c0) * 0.0625f);
            float a3 = softplus_f(fabsf(E[b3])  * (d3 + c0) * 0.0625f);
            float av = (lane == 0) ? a0 : (lane == 1) ? a1 : (lane == 2) ? a2 : a3;
            if (lane < 4) a_arr[n + lane] = av;
            if (lane == 0) {
                if (b0 != curb) { atomicAdd(&anorm[curb], accA); accA = 0.f; curb = b0; }
                accA += a0;
                if (b1i != curb) { atomicAdd(&anorm[curb], accA); accA = 0.f; curb = b1i; }
                accA += a1;
                if (b2i != curb) { atomicAdd(&anorm[curb], accA); accA = 0.f; curb = b2i; }
                accA += a2;
                if (b3 != curb) { atomicAdd(&anorm[curb], accA); accA = 0.f; curb = b3; }
                accA += a3;
            }
        }
        for (; n < n1; ++n) {
            const f4* xp = (const f4*)(x + (size_t)n * F) + lane;
            f4 r0 = xp[0];
            float d0 = r0.x * u4.x + r0.y * u4.y + r0.z * u4.z + r0.w * u4.w;
            #pragma unroll
            for (int off = 32; off; off >>= 1) d0 += __shfl_xor(d0, off);
            int b0 = seg[n];
            float a0 = softplus_f(fabsf(E[b0]) * (d0 + c0) * 0.0625f);
            if (lane == 0) {
                a_arr[n] = a0;
                if (b0 != curb) { atomicAdd(&anorm[curb], accA); accA = 0.f; curb = b0; }
                accA += a0;
            }
        }
        if (lane == 0) atomicAdd(&anorm[curb], accA);
    } else {
        const int tb = blockIdx.x;
        const int i  = threadIdx.x;
        const float delta = SMAX / (float)(TBL - 1);
        const float wv = Wv[i];

        #pragma unroll
        for (int r = 0; r < 16; ++r) {
            float s  = (float)(tb * 16 + r) * delta;
            float zv = s * wv;
            zbuf[r][i] = zv / (1.f + __expf(-zv));
        }
        __syncthreads();

        float acc[16];
        float bb = b1[i];
        #pragma unroll
        for (int r = 0; r < 16; ++r) acc[r] = bb;
        const f4* w1row = (const f4*)(W1 + (size_t)i * F);
        for (int fc = 0; fc < F / 4; ++fc) {
            f4 w4 = w1row[fc];
            #pragma unroll
            for (int r = 0; r < 16; ++r) {
                f4 z4 = *(const f4*)&zbuf[r][fc * 4];
                acc[r] += w4.x * z4.x + w4.y * z4.y + w4.z * z4.z + w4.w * z4.w;
            }
        }
        __syncthreads();
        #pragma unroll
        for (int r = 0; r < 16; ++r)
            zbuf[r][i] = acc[r] / (1.f + __expf(-acc[r]));
        __syncthreads();

        bb = b2[i];
        #pragma unroll
        for (int r = 0; r < 16; ++r) acc[r] = bb;
        const f4* w2row = (const f4*)(W2 + (size_t)i * F);
        for (int fc = 0; fc < F / 4; ++fc) {
            f4 w4 = w2row[fc];
            #pragma unroll
            for (int r = 0; r < 16; ++r) {
                f4 z4 = *(const f4*)&zbuf[r][fc * 4];
                acc[r] += w4.x * z4.x + w4.y * z4.y + w4.z * z4.z + w4.w * z4.w;
            }
        }
        #pragma unroll
        for (int r = 0; r < 16; ++r) {
            float s = (float)(tb * 16 + r) * delta;
            table[(size_t)(tb * 16 + r) * F + i] = s * wv + acc[r];
        }
    }
}

__global__ __launch_bounds__(256)
void k_out(const float* __restrict__ a_arr, const int* __restrict__ seg,
           const float* __restrict__ E, const float* __restrict__ anorm,
           const float* __restrict__ table, float* __restrict__ out, int N)
{
    const int lane = threadIdx.x & 63;
    const int wid  = threadIdx.x >> 6;
    const int S = gridDim.x * 4;
    const float inv_delta = (float)(TBL - 1) / SMAX;
    const int gw = blockIdx.x * 4 + wid;

    for (int n = gw; n < N; n += 2 * S) {
        const int n2 = n + S;
        const bool two = n2 < N;

        int b0 = seg[n];
        float a0 = a_arr[n];
        float s0 = a0 / (anorm[b0] + EPS) * fabsf(E[b0]);
        int i0 = (int)(s0 * inv_delta + 0.5f);
        i0 = min(max(i0, 0), TBL - 1);

        int i1 = 0;
        if (two) {
            int b1 = seg[n2];
            float a1 = a_arr[n2];
            float s1 = a1 / (anorm[b1] + EPS) * fabsf(E[b1]);
            i1 = (int)(s1 * inv_delta + 0.5f);
            i1 = min(max(i1, 0), TBL - 1);
        }

        const f4 g0 = ((const f4*)(table + (size_t)i0 * F))[lane];
        __builtin_nontemporal_store(g0, (f4*)(out + (size_t)n * F) + lane);
        if (two) {
            const f4 g1 = ((const f4*)(table + (size_t)i1 * F))[lane];
            __builtin_nontemporal_store(g1, (f4*)(out + (size_t)n2 * F) + lane);
        }
    }
}

extern "C" void kernel_launch(void* const* d_in, const int* in_sizes, int n_in,
                              void* d_out, int out_size, void* d_ws, size_t ws_size,
                              hipStream_t stream)
{
    const float* x   = (const float*)d_in[0];
    const float* E   = (const float*)d_in[1];
    const int*   seg = (const int*)  d_in[2];
    const float* Wq  = (const float*)d_in[4];
    const float* bq  = (const float*)d_in[5];
    const float* Wk  = (const float*)d_in[6];
    const float* Wv  = (const float*)d_in[7];
    const float* W1  = (const float*)d_in[8];
    const float* b1  = (const float*)d_in[9];
    const float* W2  = (const float*)d_in[10];
    const float* b2  = (const float*)d_in[11];

    const int N = in_sizes[0] / F;
    const int B = in_sizes[1];
    float* out = (float*)d_out;

    float* ws    = (float*)d_ws;
    float* table = ws;                          // TBL*F floats (4 MB)
    float* u     = table + (size_t)TBL * F;     // F
    float* c0    = u + F;                       // 1 (padded to 4)
    float* anorm = c0 + 4;                      // B
    float* a_arr = anorm + B;                   // N

    k_prep<<<1, 256, 0, stream>>>(Wq, bq, Wk, u, c0, anorm, B);

    k_main<<<TBLK + GA, 256, 0, stream>>>(x, E, seg, u, c0, Wv, W1, b1, W2,
                                          b2, a_arr, anorm, table, N);

    k_out<<<2048, 256, 0, stream>>>(a_arr, seg, E, anorm, table, out, N);
}

// Round 6
// 164.878 us; speedup vs baseline: 1.2213x; 1.0690x over previous
//
#include <hip/hip_runtime.h>
#include <math.h>

#define F 256
#define TBL 2048
#define TBLK (TBL / 16)      // 128 table-builder blocks
#define GA (2048 - TBLK)     // 1920 phase-A blocks (one residency round total)
#define SMAX 8.0f
#define EPS 1e-8f

typedef float f4 __attribute__((ext_vector_type(4)));

__device__ __forceinline__ float softplus_f(float t) {
    return fmaxf(t, 0.f) + log1pf(expf(-fabsf(t)));
}

// ---------------------------------------------------------------------------
// k_prep: u[g] = sum_f Wk[f]*Wq[f,g];  c0 = Wk.bq;  zero anorm
// ---------------------------------------------------------------------------
__global__ __launch_bounds__(256)
void k_prep(const float* __restrict__ Wq, const float* __restrict__ bq,
            const float* __restrict__ Wk, float* __restrict__ u,
            float* __restrict__ c0, float* __restrict__ anorm, int B)
{
    __shared__ float wk_s[F];
    __shared__ float red[F];
    int g = threadIdx.x;
    for (int j = g; j < B; j += 256) anorm[j] = 0.f;
    wk_s[g] = Wk[g];
    __syncthreads();
    float acc = 0.f;
    #pragma unroll 4
    for (int f = 0; f < F; ++f)
        acc += wk_s[f] * Wq[f * F + g];
    u[g] = acc;

    red[g] = wk_s[g] * bq[g];
    __syncthreads();
    for (int s = 128; s > 0; s >>= 1) {
        if (g < s) red[g] += red[g + s];
        __syncthreads();
    }
    if (g == 0) *c0 = red[0];
}

// ---------------------------------------------------------------------------
// k_main: blocks [0,TBLK): lookup table g(s)=s*Wv+h2(s), 16 rows/block
//         blocks [TBLK,TBLK+GA): phase A — a[n]=softplus(.), anorm seg-sum
// ---------------------------------------------------------------------------
__global__ __launch_bounds__(256)
void k_main(const float* __restrict__ x, const float* __restrict__ E,
            const int* __restrict__ seg, const float* __restrict__ u,
            const float* __restrict__ c0p, const float* __restrict__ Wv,
            const float* __restrict__ W1, const float* __restrict__ b1,
            const float* __restrict__ W2, const float* __restrict__ b2,
            float* __restrict__ a_arr, float* __restrict__ anorm,
            float* __restrict__ table, int N)
{
    __shared__ float zbuf[16][F];   // 16 KB (table blocks only)

    if ((int)blockIdx.x >= TBLK) {
        // ----- phase A: contiguous chunk per wave, 4 rows/iter, NT loads -----
        const int lane = threadIdx.x & 63;
        const int wid  = threadIdx.x >> 6;
        const int gwave = (blockIdx.x - TBLK) * 4 + wid;
        const int total_waves = GA * 4;
        const int chunk = (N + total_waves - 1) / total_waves;
        const int n0 = gwave * chunk;
        const int n1 = min(n0 + chunk, N);
        if (n0 >= n1) return;

        const f4 u4 = ((const f4*)u)[lane];
        const float c0 = *c0p;

        int   curb = seg[n0];
        float accA = 0.f;

        int n = n0;
        for (; n + 3 < n1; n += 4) {
            const f4* xp = (const f4*)(x + (size_t)n * F) + lane;
            f4 r0 = __builtin_nontemporal_load(xp);
            f4 r1 = __builtin_nontemporal_load(xp + 64);
            f4 r2 = __builtin_nontemporal_load(xp + 128);
            f4 r3 = __builtin_nontemporal_load(xp + 192);
            float d0 = r0.x * u4.x + r0.y * u4.y + r0.z * u4.z + r0.w * u4.w;
            float d1 = r1.x * u4.x + r1.y * u4.y + r1.z * u4.z + r1.w * u4.w;
            float d2 = r2.x * u4.x + r2.y * u4.y + r2.z * u4.z + r2.w * u4.w;
            float d3 = r3.x * u4.x + r3.y * u4.y + r3.z * u4.z + r3.w * u4.w;
            #pragma unroll
            for (int off = 32; off; off >>= 1) {
                d0 += __shfl_xor(d0, off);
                d1 += __shfl_xor(d1, off);
                d2 += __shfl_xor(d2, off);
                d3 += __shfl_xor(d3, off);
            }
            int b0 = seg[n], b1i = seg[n + 1], b2i = seg[n + 2], b3 = seg[n + 3];
            float a0 = softplus_f(fabsf(E[b0])  * (d0 + c0) * 0.0625f);
            float a1 = softplus_f(fabsf(E[b1i]) * (d1 + c0) * 0.0625f);
            float a2 = softplus_f(fabsf(E[b2i]) * (d2 + c0) * 0.0625f);
            float a3 = softplus_f(fabsf(E[b3])  * (d3 + c0) * 0.0625f);
            float av = (lane == 0) ? a0 : (lane == 1) ? a1 : (lane == 2) ? a2 : a3;
            if (lane < 4) a_arr[n + lane] = av;
            if (lane == 0) {
                if (b0 != curb) { atomicAdd(&anorm[curb], accA); accA = 0.f; curb = b0; }
                accA += a0;
                if (b1i != curb) { atomicAdd(&anorm[curb], accA); accA = 0.f; curb = b1i; }
                accA += a1;
                if (b2i != curb) { atomicAdd(&anorm[curb], accA); accA = 0.f; curb = b2i; }
                accA += a2;
                if (b3 != curb) { atomicAdd(&anorm[curb], accA); accA = 0.f; curb = b3; }
                accA += a3;
            }
        }
        for (; n < n1; ++n) {
            const f4* xp = (const f4*)(x + (size_t)n * F) + lane;
            f4 r0 = __builtin_nontemporal_load(xp);
            float d0 = r0.x * u4.x + r0.y * u4.y + r0.z * u4.z + r0.w * u4.w;
            #pragma unroll
            for (int off = 32; off; off >>= 1) d0 += __shfl_xor(d0, off);
            int b0 = seg[n];
            float a0 = softplus_f(fabsf(E[b0]) * (d0 + c0) * 0.0625f);
            if (lane == 0) {
                a_arr[n] = a0;
                if (b0 != curb) { atomicAdd(&anorm[curb], accA); accA = 0.f; curb = b0; }
                accA += a0;
            }
        }
        if (lane == 0) atomicAdd(&anorm[curb], accA);
    } else {
        // ----- table build -----
        const int tb = blockIdx.x;
        const int i  = threadIdx.x;
        const float delta = SMAX / (float)(TBL - 1);
        const float wv = Wv[i];

        #pragma unroll
        for (int r = 0; r < 16; ++r) {
            float s  = (float)(tb * 16 + r) * delta;
            float zv = s * wv;
            zbuf[r][i] = zv / (1.f + __expf(-zv));               // silu(y)
        }
        __syncthreads();

        float acc[16];
        float bb = b1[i];
        #pragma unroll
        for (int r = 0; r < 16; ++r) acc[r] = bb;
        const f4* w1row = (const f4*)(W1 + (size_t)i * F);
        for (int fc = 0; fc < F / 4; ++fc) {
            f4 w4 = w1row[fc];
            #pragma unroll
            for (int r = 0; r < 16; ++r) {
                f4 z4 = *(const f4*)&zbuf[r][fc * 4];
                acc[r] += w4.x * z4.x + w4.y * z4.y + w4.z * z4.z + w4.w * z4.w;
            }
        }
        __syncthreads();
        #pragma unroll
        for (int r = 0; r < 16; ++r)
            zbuf[r][i] = acc[r] / (1.f + __expf(-acc[r]));       // silu(h1)
        __syncthreads();

        bb = b2[i];
        #pragma unroll
        for (int r = 0; r < 16; ++r) acc[r] = bb;
        const f4* w2row = (const f4*)(W2 + (size_t)i * F);
        for (int fc = 0; fc < F / 4; ++fc) {
            f4 w4 = w2row[fc];
            #pragma unroll
            for (int r = 0; r < 16; ++r) {
                f4 z4 = *(const f4*)&zbuf[r][fc * 4];
                acc[r] += w4.x * z4.x + w4.y * z4.y + w4.z * z4.z + w4.w * z4.w;
            }
        }
        #pragma unroll
        for (int r = 0; r < 16; ++r) {
            float s = (float)(tb * 16 + r) * delta;
            table[(size_t)(tb * 16 + r) * F + i] = s * wv + acc[r];
        }
    }
}

// ---------------------------------------------------------------------------
// k_out: chunk-contiguous rows per wave. Lane-parallel index precompute
// (lane l -> row t+l), then per row: shfl idx, gather 1KB table row, NT store.
// ---------------------------------------------------------------------------
__global__ __launch_bounds__(256)
void k_out(const float* __restrict__ a_arr, const int* __restrict__ seg,
           const float* __restrict__ E, const float* __restrict__ anorm,
           const float* __restrict__ table, float* __restrict__ out, int N)
{
    const int lane = threadIdx.x & 63;
    const int wid  = threadIdx.x >> 6;
    const int gw   = blockIdx.x * 4 + wid;
    const int waves = gridDim.x * 4;
    const int chunk = (N + waves - 1) / waves;
    const int m0 = gw * chunk;
    const int m1 = min(m0 + chunk, N);
    if (m0 >= m1) return;
    const float inv_delta = (float)(TBL - 1) / SMAX;

    for (int t = m0; t < m1; t += 64) {
        const int cnt = min(64, m1 - t);
        // lane-parallel scalar pipeline: lane l handles row t+l
        int idx = 0;
        if (lane < cnt) {
            int r = t + lane;
            int b = seg[r];                       // coalesced
            float a = a_arr[r];                   // coalesced
            float s = a / (anorm[b] + EPS) * fabsf(E[b]);
            int i0 = (int)(s * inv_delta + 0.5f);
            i0 = min(max(i0, 0), TBL - 1);
            idx = i0 * F;
        }
        int r = 0;
        for (; r + 3 < cnt; r += 4) {
            int i0 = __shfl(idx, r);
            int i1 = __shfl(idx, r + 1);
            int i2 = __shfl(idx, r + 2);
            int i3 = __shfl(idx, r + 3);
            f4 g0 = ((const f4*)(table + i0))[lane];
            f4 g1 = ((const f4*)(table + i1))[lane];
            f4 g2 = ((const f4*)(table + i2))[lane];
            f4 g3 = ((const f4*)(table + i3))[lane];
            __builtin_nontemporal_store(g0, (f4*)(out + (size_t)(t + r)     * F) + lane);
            __builtin_nontemporal_store(g1, (f4*)(out + (size_t)(t + r + 1) * F) + lane);
            __builtin_nontemporal_store(g2, (f4*)(out + (size_t)(t + r + 2) * F) + lane);
            __builtin_nontemporal_store(g3, (f4*)(out + (size_t)(t + r + 3) * F) + lane);
        }
        for (; r < cnt; ++r) {
            int i0 = __shfl(idx, r);
            f4 g0 = ((const f4*)(table + i0))[lane];
            __builtin_nontemporal_store(g0, (f4*)(out + (size_t)(t + r) * F) + lane);
        }
    }
}

// ---------------------------------------------------------------------------
extern "C" void kernel_launch(void* const* d_in, const int* in_sizes, int n_in,
                              void* d_out, int out_size, void* d_ws, size_t ws_size,
                              hipStream_t stream)
{
    const float* x   = (const float*)d_in[0];
    const float* E   = (const float*)d_in[1];
    const int*   seg = (const int*)  d_in[2];
    const float* Wq  = (const float*)d_in[4];
    const float* bq  = (const float*)d_in[5];
    const float* Wk  = (const float*)d_in[6];
    const float* Wv  = (const float*)d_in[7];
    const float* W1  = (const float*)d_in[8];
    const float* b1  = (const float*)d_in[9];
    const float* W2  = (const float*)d_in[10];
    const float* b2  = (const float*)d_in[11];

    const int N = in_sizes[0] / F;
    const int B = in_sizes[1];
    float* out = (float*)d_out;

    float* ws    = (float*)d_ws;
    float* table = ws;                          // TBL*F floats (2 MB)
    float* u     = table + (size_t)TBL * F;     // F
    float* c0    = u + F;                       // 1 (padded to 4)
    float* anorm = c0 + 4;                      // B
    float* a_arr = anorm + B;                   // N

    k_prep<<<1, 256, 0, stream>>>(Wq, bq, Wk, u, c0, anorm, B);

    k_main<<<TBLK + GA, 256, 0, stream>>>(x, E, seg, u, c0, Wv, W1, b1, W2,
                                          b2, a_arr, anorm, table, N);

    k_out<<<2048, 256, 0, stream>>>(a_arr, seg, E, anorm, table, out, N);
}

// Round 7
// 159.302 us; speedup vs baseline: 1.2640x; 1.0350x over previous
//
#include <hip/hip_runtime.h>
#include <math.h>

#define F 256
#define TBL 2048
#define TBLK (TBL / 16)      // 128 table-builder blocks
#define GA (2048 - TBLK)     // 1920 phase-A blocks (one residency round total)
#define SMAX 8.0f
#define EPS 1e-8f

typedef float f4 __attribute__((ext_vector_type(4)));

__device__ __forceinline__ float softplus_f(float t) {
    return fmaxf(t, 0.f) + log1pf(expf(-fabsf(t)));
}

// ---------------------------------------------------------------------------
// k_prep (wide): block g<F computes u[g] = sum_f Wk[f]*Wq[f,g] via 256-thread
// reduce; block F computes c0 = Wk.bq. anorm zeroed across the grid.
// ---------------------------------------------------------------------------
__global__ __launch_bounds__(256)
void k_prep(const float* __restrict__ Wq, const float* __restrict__ bq,
            const float* __restrict__ Wk, float* __restrict__ u,
            float* __restrict__ c0, float* __restrict__ anorm, int B)
{
    __shared__ float red[256];
    const int t = threadIdx.x;
    const int g = blockIdx.x;

    int j = g * 256 + t;
    if (j < B) anorm[j] = 0.f;

    float p;
    if (g < F) p = Wk[t] * Wq[(size_t)t * F + g];
    else       p = Wk[t] * bq[t];
    red[t] = p;
    __syncthreads();
    #pragma unroll
    for (int s = 128; s > 0; s >>= 1) {
        if (t < s) red[t] += red[t + s];
        __syncthreads();
    }
    if (t == 0) {
        if (g < F) u[g] = red[0];
        else       *c0 = red[0];
    }
}

// ---------------------------------------------------------------------------
// k_main: blocks [0,TBLK): lookup table g(s)=s*Wv+h2(s), 16 rows/block
//         blocks [TBLK,TBLK+GA): phase A — a[n]=softplus(.), anorm seg-sum
// ---------------------------------------------------------------------------
__global__ __launch_bounds__(256)
void k_main(const float* __restrict__ x, const float* __restrict__ E,
            const int* __restrict__ seg, const float* __restrict__ u,
            const float* __restrict__ c0p, const float* __restrict__ Wv,
            const float* __restrict__ W1, const float* __restrict__ b1,
            const float* __restrict__ W2, const float* __restrict__ b2,
            float* __restrict__ a_arr, float* __restrict__ anorm,
            float* __restrict__ table, int N)
{
    __shared__ float zbuf[16][F];   // 16 KB (table blocks only)

    if ((int)blockIdx.x >= TBLK) {
        // ----- phase A: contiguous chunk per wave, 4 rows/iter, NT loads -----
        const int lane = threadIdx.x & 63;
        const int wid  = threadIdx.x >> 6;
        const int gwave = (blockIdx.x - TBLK) * 4 + wid;
        const int total_waves = GA * 4;
        const int chunk = (N + total_waves - 1) / total_waves;
        const int n0 = gwave * chunk;
        const int n1 = min(n0 + chunk, N);
        if (n0 >= n1) return;

        const f4 u4 = ((const f4*)u)[lane];
        const float c0 = *c0p;

        int   curb = seg[n0];
        float accA = 0.f;

        int n = n0;
        for (; n + 3 < n1; n += 4) {
            const f4* xp = (const f4*)(x + (size_t)n * F) + lane;
            f4 r0 = __builtin_nontemporal_load(xp);
            f4 r1 = __builtin_nontemporal_load(xp + 64);
            f4 r2 = __builtin_nontemporal_load(xp + 128);
            f4 r3 = __builtin_nontemporal_load(xp + 192);
            float d0 = r0.x * u4.x + r0.y * u4.y + r0.z * u4.z + r0.w * u4.w;
            float d1 = r1.x * u4.x + r1.y * u4.y + r1.z * u4.z + r1.w * u4.w;
            float d2 = r2.x * u4.x + r2.y * u4.y + r2.z * u4.z + r2.w * u4.w;
            float d3 = r3.x * u4.x + r3.y * u4.y + r3.z * u4.z + r3.w * u4.w;
            #pragma unroll
            for (int off = 32; off; off >>= 1) {
                d0 += __shfl_xor(d0, off);
                d1 += __shfl_xor(d1, off);
                d2 += __shfl_xor(d2, off);
                d3 += __shfl_xor(d3, off);
            }
            int b0 = seg[n], b1i = seg[n + 1], b2i = seg[n + 2], b3 = seg[n + 3];
            float a0 = softplus_f(fabsf(E[b0])  * (d0 + c0) * 0.0625f);
            float a1 = softplus_f(fabsf(E[b1i]) * (d1 + c0) * 0.0625f);
            float a2 = softplus_f(fabsf(E[b2i]) * (d2 + c0) * 0.0625f);
            float a3 = softplus_f(fabsf(E[b3])  * (d3 + c0) * 0.0625f);
            float av = (lane == 0) ? a0 : (lane == 1) ? a1 : (lane == 2) ? a2 : a3;
            if (lane < 4) a_arr[n + lane] = av;
            if (lane == 0) {
                if (b0 != curb) { atomicAdd(&anorm[curb], accA); accA = 0.f; curb = b0; }
                accA += a0;
                if (b1i != curb) { atomicAdd(&anorm[curb], accA); accA = 0.f; curb = b1i; }
                accA += a1;
                if (b2i != curb) { atomicAdd(&anorm[curb], accA); accA = 0.f; curb = b2i; }
                accA += a2;
                if (b3 != curb) { atomicAdd(&anorm[curb], accA); accA = 0.f; curb = b3; }
                accA += a3;
            }
        }
        for (; n < n1; ++n) {
            const f4* xp = (const f4*)(x + (size_t)n * F) + lane;
            f4 r0 = __builtin_nontemporal_load(xp);
            float d0 = r0.x * u4.x + r0.y * u4.y + r0.z * u4.z + r0.w * u4.w;
            #pragma unroll
            for (int off = 32; off; off >>= 1) d0 += __shfl_xor(d0, off);
            int b0 = seg[n];
            float a0 = softplus_f(fabsf(E[b0]) * (d0 + c0) * 0.0625f);
            if (lane == 0) {
                a_arr[n] = a0;
                if (b0 != curb) { atomicAdd(&anorm[curb], accA); accA = 0.f; curb = b0; }
                accA += a0;
            }
        }
        if (lane == 0) atomicAdd(&anorm[curb], accA);
    } else {
        // ----- table build -----
        const int tb = blockIdx.x;
        const int i  = threadIdx.x;
        const float delta = SMAX / (float)(TBL - 1);
        const float wv = Wv[i];

        #pragma unroll
        for (int r = 0; r < 16; ++r) {
            float s  = (float)(tb * 16 + r) * delta;
            float zv = s * wv;
            zbuf[r][i] = zv / (1.f + __expf(-zv));               // silu(y)
        }
        __syncthreads();

        float acc[16];
        float bb = b1[i];
        #pragma unroll
        for (int r = 0; r < 16; ++r) acc[r] = bb;
        const f4* w1row = (const f4*)(W1 + (size_t)i * F);
        for (int fc = 0; fc < F / 4; ++fc) {
            f4 w4 = w1row[fc];
            #pragma unroll
            for (int r = 0; r < 16; ++r) {
                f4 z4 = *(const f4*)&zbuf[r][fc * 4];
                acc[r] += w4.x * z4.x + w4.y * z4.y + w4.z * z4.z + w4.w * z4.w;
            }
        }
        __syncthreads();
        #pragma unroll
        for (int r = 0; r < 16; ++r)
            zbuf[r][i] = acc[r] / (1.f + __expf(-acc[r]));       // silu(h1)
        __syncthreads();

        bb = b2[i];
        #pragma unroll
        for (int r = 0; r < 16; ++r) acc[r] = bb;
        const f4* w2row = (const f4*)(W2 + (size_t)i * F);
        for (int fc = 0; fc < F / 4; ++fc) {
            f4 w4 = w2row[fc];
            #pragma unroll
            for (int r = 0; r < 16; ++r) {
                f4 z4 = *(const f4*)&zbuf[r][fc * 4];
                acc[r] += w4.x * z4.x + w4.y * z4.y + w4.z * z4.z + w4.w * z4.w;
            }
        }
        #pragma unroll
        for (int r = 0; r < 16; ++r) {
            float s = (float)(tb * 16 + r) * delta;
            table[(size_t)(tb * 16 + r) * F + i] = s * wv + acc[r];
        }
    }
}

// ---------------------------------------------------------------------------
// k_out: chunk-contiguous rows per wave. Lane-parallel index precompute
// (lane l -> row t+l), then per row: shfl idx, gather 1KB table row, NT store.
// ---------------------------------------------------------------------------
__global__ __launch_bounds__(256)
void k_out(const float* __restrict__ a_arr, const int* __restrict__ seg,
           const float* __restrict__ E, const float* __restrict__ anorm,
           const float* __restrict__ table, float* __restrict__ out, int N)
{
    const int lane = threadIdx.x & 63;
    const int wid  = threadIdx.x >> 6;
    const int gw   = blockIdx.x * 4 + wid;
    const int waves = gridDim.x * 4;
    const int chunk = (N + waves - 1) / waves;
    const int m0 = gw * chunk;
    const int m1 = min(m0 + chunk, N);
    if (m0 >= m1) return;
    const float inv_delta = (float)(TBL - 1) / SMAX;

    for (int t = m0; t < m1; t += 64) {
        const int cnt = min(64, m1 - t);
        int idx = 0;
        if (lane < cnt) {
            int r = t + lane;
            int b = seg[r];                       // coalesced
            float a = a_arr[r];                   // coalesced
            float s = a / (anorm[b] + EPS) * fabsf(E[b]);
            int i0 = (int)(s * inv_delta + 0.5f);
            i0 = min(max(i0, 0), TBL - 1);
            idx = i0 * F;
        }
        int r = 0;
        for (; r + 3 < cnt; r += 4) {
            int i0 = __shfl(idx, r);
            int i1 = __shfl(idx, r + 1);
            int i2 = __shfl(idx, r + 2);
            int i3 = __shfl(idx, r + 3);
            f4 g0 = ((const f4*)(table + i0))[lane];
            f4 g1 = ((const f4*)(table + i1))[lane];
            f4 g2 = ((const f4*)(table + i2))[lane];
            f4 g3 = ((const f4*)(table + i3))[lane];
            __builtin_nontemporal_store(g0, (f4*)(out + (size_t)(t + r)     * F) + lane);
            __builtin_nontemporal_store(g1, (f4*)(out + (size_t)(t + r + 1) * F) + lane);
            __builtin_nontemporal_store(g2, (f4*)(out + (size_t)(t + r + 2) * F) + lane);
            __builtin_nontemporal_store(g3, (f4*)(out + (size_t)(t + r + 3) * F) + lane);
        }
        for (; r < cnt; ++r) {
            int i0 = __shfl(idx, r);
            f4 g0 = ((const f4*)(table + i0))[lane];
            __builtin_nontemporal_store(g0, (f4*)(out + (size_t)(t + r) * F) + lane);
        }
    }
}

// ---------------------------------------------------------------------------
extern "C" void kernel_launch(void* const* d_in, const int* in_sizes, int n_in,
                              void* d_out, int out_size, void* d_ws, size_t ws_size,
                              hipStream_t stream)
{
    const float* x   = (const float*)d_in[0];
    const float* E   = (const float*)d_in[1];
    const int*   seg = (const int*)  d_in[2];
    const float* Wq  = (const float*)d_in[4];
    const float* bq  = (const float*)d_in[5];
    const float* Wk  = (const float*)d_in[6];
    const float* Wv  = (const float*)d_in[7];
    const float* W1  = (const float*)d_in[8];
    const float* b1  = (const float*)d_in[9];
    const float* W2  = (const float*)d_in[10];
    const float* b2  = (const float*)d_in[11];

    const int N = in_sizes[0] / F;
    const int B = in_sizes[1];
    float* out = (float*)d_out;

    float* ws    = (float*)d_ws;
    float* table = ws;                          // TBL*F floats (2 MB)
    float* u     = table + (size_t)TBL * F;     // F
    float* c0    = u + F;                       // 1 (padded to 4)
    float* anorm = c0 + 4;                      // B
    float* a_arr = anorm + B;                   // N

    k_prep<<<F + 1, 256, 0, stream>>>(Wq, bq, Wk, u, c0, anorm, B);

    k_main<<<TBLK + GA, 256, 0, stream>>>(x, E, seg, u, c0, Wv, W1, b1, W2,
                                          b2, a_arr, anorm, table, N);

    k_out<<<2048, 256, 0, stream>>>(a_arr, seg, E, anorm, table, out, N);
}